// Round 7
// baseline (744.932 us; speedup 1.0000x reference)
//
#include <hip/hip_runtime.h>

// SignalingModel: X_{t+1} = mml(W @ X_t + X_bias), 60 steps, W 0.24% sparse.
// R4: atomic-free target-ownership GATHER. Thread t owns nodes {2t,2t+1};
// reads its contiguous CSR in-edge range (w,src) from L2, gathers X[src] from
// LDS, accumulates in registers, one plain float2 store, ONE barrier/step.
// LDS = 16KB state only -> 2 blocks/CU (32 waves/CU, max occupancy).
// R1-R3 lessons: LDS atomics ~25cyc effective (R1/R3), compiler won't keep
// edge arrays in VGPRs (VGPR=36/76/28), occupancy alone didn't help (R3).

#define NN 2048
#define STEPS 60
#define LEAKV 0.01f
#define EMAX 10240          // E; actual nnz <= EMAX (duplicate (tgt,src) collapse)
#define TPB 1024

__device__ __forceinline__ float mml_f(float x) {
  if (x < 0.0f)      return LEAKV * x;
  else if (x < 0.5f) return x;
  else               return 1.0f - 0.25f / x;
}

// --- build pipeline: CSR by target (edges sorted by (tgt,src)) ------------

__global__ __launch_bounds__(64) void count_row(const float* __restrict__ W,
                                                int* __restrict__ cnt) {
  const int n = blockIdx.x, lane = threadIdx.x;
  int c = 0;
  for (int c0 = 0; c0 < NN; c0 += 64) {
    float w = W[n * NN + c0 + lane];
    c += __popcll(__ballot(w != 0.0f));
  }
  if (lane == 0) cnt[n] = c;
}

// exclusive scan of 2048 counts -> row starts; sentinel base[NN] = nnz
__global__ __launch_bounds__(1024) void scan2048(const int* __restrict__ cnt,
                                                 int* __restrict__ base) {
  __shared__ int sb[2][NN];
  const int t = threadIdx.x;
  sb[0][t] = cnt[t];
  sb[0][t + 1024] = cnt[t + 1024];
  __syncthreads();
  int p = 0;
  for (int off = 1; off < NN; off <<= 1) {
    int i0 = t, i1 = t + 1024;
    sb[p ^ 1][i0] = sb[p][i0] + (i0 >= off ? sb[p][i0 - off] : 0);
    sb[p ^ 1][i1] = sb[p][i1] + (i1 >= off ? sb[p][i1 - off] : 0);
    __syncthreads();
    p ^= 1;
  }
  base[t] = sb[p][t] - cnt[t];
  base[t + 1024] = sb[p][t + 1024] - cnt[t + 1024];
  if (t == 1023) base[NN] = sb[p][NN - 1];   // total nnz
}

// entry e = (w_bits, src), written at global ordinal (row-major scan order)
__global__ __launch_bounds__(64) void fill_edges(const float* __restrict__ W,
                                                 const int* __restrict__ base,
                                                 uint2* __restrict__ pg) {
  const int n = blockIdx.x, lane = threadIdx.x;
  const int b = base[n];
  int off = 0;
  for (int c0 = 0; c0 < NN; c0 += 64) {
    float w = W[n * NN + c0 + lane];
    unsigned long long m = __ballot(w != 0.0f);
    if (w != 0.0f) {
      int e = b + off + __popcll(m & ((1ull << lane) - 1ull));
      pg[e] = make_uint2(__float_as_uint(w), (unsigned)(c0 + lane));
    }
    off += __popcll(m);
  }
}

// --- simulation -----------------------------------------------------------
// one block per sample; thread t owns nodes {2t, 2t+1}; fused contiguous
// edge loop over [base[2t], base[2t+2]) with mid-split select.
__global__ __launch_bounds__(TPB, 8) void sim(const float* __restrict__ Xfull,
                                              const float* __restrict__ bias,
                                              const uint2* __restrict__ pg,
                                              const int* __restrict__ base,
                                              float* __restrict__ out) {
  __shared__ float X2[2][NN];
  const int t = (int)threadIdx.x;
  const int s = (int)blockIdx.x;
  const int n0 = 2 * t;

  const int b0 = base[n0];
  const int bm = base[n0 + 1];
  const int b2 = base[n0 + 2];

  float2 xb;
  {
    float2 a  = *(const float2*)&Xfull[(size_t)s * NN + n0];
    float2 bv = *(const float2*)&bias[n0];
    xb = make_float2(a.x + bv.x, a.y + bv.y);
  }
  // X1 = mml(W@0 + xb) = mml(xb)
  *(float2*)&X2[0][n0] = make_float2(mml_f(xb.x), mml_f(xb.y));
  __syncthreads();

  int cur = 0;
  float y0 = mml_f(xb.x), y1 = mml_f(xb.y);
  for (int it = 0; it < STEPS - 1; ++it) {   // produces X2..X60
    const float* __restrict__ Xc = X2[cur];
    float a0 = xb.x, a1 = xb.y;
    for (int e = b0; e < b2; ++e) {
      const uint2 en = pg[e];                       // (w, src) from L2
      const float v = __uint_as_float(en.x) * Xc[en.y];  // LDS gather
      const bool first = (e < bm);
      a0 += first ? v : 0.0f;
      a1 += first ? 0.0f : v;
    }
    y0 = mml_f(a0); y1 = mml_f(a1);
    *(float2*)&X2[cur ^ 1][n0] = make_float2(y0, y1);  // exclusive store
    __syncthreads();                                   // one barrier per step
    cur ^= 1;
  }

  // final values still in registers
  *(float2*)&out[(size_t)s * NN + n0] = make_float2(y0, y1);
}

extern "C" void kernel_launch(void* const* d_in, const int* in_sizes, int n_in,
                              void* d_out, int out_size, void* d_ws, size_t ws_size,
                              hipStream_t stream) {
  const float* Xfull = (const float*)d_in[0];   // (B, N) f32
  const float* W     = (const float*)d_in[1];   // (N, N) f32
  const float* bias  = (const float*)d_in[2];   // (N, 1) f32
  float* out = (float*)d_out;

  // ws: pg[EMAX] uint2 (80KB) | cnt[NN] i32 | base[NN+1] i32
  char* ws = (char*)d_ws;
  uint2* pg = (uint2*)ws;
  int* cnt  = (int*)(ws + (size_t)EMAX * 8);
  int* base = (int*)(ws + (size_t)EMAX * 8 + (size_t)NN * 4);

  const int B = in_sizes[0] / NN;   // 512

  count_row<<<NN, 64, 0, stream>>>(W, cnt);
  scan2048<<<1, 1024, 0, stream>>>(cnt, base);
  fill_edges<<<NN, 64, 0, stream>>>(W, base, pg);
  sim<<<B, TPB, 0, stream>>>(Xfull, bias, pg, base, out);
}

// Round 8
// 185.654 us; speedup vs baseline: 4.0125x; 4.0125x over previous
//
#include <hip/hip_runtime.h>

// SignalingModel: X_{t+1} = mml(W @ X_t + X_bias), 60 steps, W 0.24% sparse.
// R5 = R3's LDS-resident edges + R4's atomic-free gather ownership.
// CSR entries (w,src) staged to LDS once (80KB); thread t owns nodes {2t,2t+1},
// gathers from LDS state, accumulates in regs, one float2 store, ONE barrier
// per step. 2 samples/block share entry reads; grid=256 = 1 block/CU.
// Lessons: LDS atomics ~16-25cy (R1/R3); per-step global structure re-reads
// = ~20x transaction expansion (R4); compiler won't hold edges in VGPRs (R1-R3).

#define NN 2048
#define STEPS 60
#define LEAKV 0.01f
#define EMAX 10240
#define TPB 1024
#define SPB 2
#define LDS_ENTRIES (EMAX * 8)                       // 81920 B
#define LDS_TOTAL (LDS_ENTRIES + SPB * 2 * NN * 4)   // 114688 B (112 KB)

__device__ __forceinline__ float mml_f(float x) {
  if (x < 0.0f)      return LEAKV * x;
  else if (x < 0.5f) return x;
  else               return 1.0f - 0.25f / x;
}

// --- build pipeline: CSR by target (edges sorted by (tgt,src)) ------------

__global__ __launch_bounds__(64) void count_row(const float* __restrict__ W,
                                                int* __restrict__ cnt) {
  const int n = blockIdx.x, lane = threadIdx.x;
  int c = 0;
  for (int c0 = 0; c0 < NN; c0 += 64) {
    float w = W[n * NN + c0 + lane];
    c += __popcll(__ballot(w != 0.0f));
  }
  if (lane == 0) cnt[n] = c;
}

__global__ __launch_bounds__(1024) void scan2048(const int* __restrict__ cnt,
                                                 int* __restrict__ base) {
  __shared__ int sb[2][NN];
  const int t = threadIdx.x;
  sb[0][t] = cnt[t];
  sb[0][t + 1024] = cnt[t + 1024];
  __syncthreads();
  int p = 0;
  for (int off = 1; off < NN; off <<= 1) {
    int i0 = t, i1 = t + 1024;
    sb[p ^ 1][i0] = sb[p][i0] + (i0 >= off ? sb[p][i0 - off] : 0);
    sb[p ^ 1][i1] = sb[p][i1] + (i1 >= off ? sb[p][i1 - off] : 0);
    __syncthreads();
    p ^= 1;
  }
  base[t] = sb[p][t] - cnt[t];
  base[t + 1024] = sb[p][t + 1024] - cnt[t + 1024];
  if (t == 1023) base[NN] = sb[p][NN - 1];   // total nnz
}

__global__ __launch_bounds__(64) void fill_edges(const float* __restrict__ W,
                                                 const int* __restrict__ base,
                                                 uint2* __restrict__ pg) {
  const int n = blockIdx.x, lane = threadIdx.x;
  const int b = base[n];
  int off = 0;
  for (int c0 = 0; c0 < NN; c0 += 64) {
    float w = W[n * NN + c0 + lane];
    unsigned long long m = __ballot(w != 0.0f);
    if (w != 0.0f) {
      int e = b + off + __popcll(m & ((1ull << lane) - 1ull));
      pg[e] = make_uint2(__float_as_uint(w), (unsigned)(c0 + lane));
    }
    off += __popcll(m);
  }
}

// --- simulation -----------------------------------------------------------

__global__ __launch_bounds__(TPB) void sim(const float* __restrict__ Xfull,
                                           const float* __restrict__ bias,
                                           const uint2* __restrict__ pg,
                                           const int* __restrict__ base,
                                           float* __restrict__ out) {
  extern __shared__ char smem[];
  uint2* E  = (uint2*)smem;                       // [EMAX] CSR entries
  float* X0 = (float*)(smem + LDS_ENTRIES);       // [2][NN] sample 0
  float* X1 = X0 + 2 * NN;                        // [2][NN] sample 1

  const int t  = (int)threadIdx.x;
  const int s0 = (int)blockIdx.x * SPB;
  const int n0 = 2 * t;

  // one-time stage: coalesced global b64 -> linear LDS (2-way alias, free)
#pragma unroll
  for (int i = 0; i < EMAX / TPB; ++i) {
    const int e = i * TPB + t;
    E[e] = pg[e];
  }

  const int b0 = base[n0];
  const int bm = base[n0 + 1];
  const int b2 = base[n0 + 2];

  float2 xb0, xb1;
  {
    const float2 bv = *(const float2*)&bias[n0];
    float2 a = *(const float2*)&Xfull[(size_t)s0 * NN + n0];
    float2 c = *(const float2*)&Xfull[(size_t)(s0 + 1) * NN + n0];
    xb0 = make_float2(a.x + bv.x, a.y + bv.y);
    xb1 = make_float2(c.x + bv.x, c.y + bv.y);
  }
  // X1 = mml(W@0 + xb) = mml(xb)
  *(float2*)&X0[n0] = make_float2(mml_f(xb0.x), mml_f(xb0.y));
  *(float2*)&X1[n0] = make_float2(mml_f(xb1.x), mml_f(xb1.y));
  __syncthreads();

  int cur = 0;
  float y00 = 0.f, y01 = 0.f, y10 = 0.f, y11 = 0.f;
  for (int it = 0; it < STEPS - 1; ++it) {   // produces X2..X60
    const float* __restrict__ c0 = X0 + cur * NN;
    const float* __restrict__ c1 = X1 + cur * NN;
    float a00 = xb0.x, a01 = xb0.y, a10 = xb1.x, a11 = xb1.y;
    for (int e = b0; e < b2; ++e) {
      const uint2 en = E[e];                     // LDS CSR entry
      const float w  = __uint_as_float(en.x);
      const float v0 = w * c0[en.y];             // LDS gathers, ~2-way banks
      const float v1 = w * c1[en.y];
      const bool first = (e < bm);
      a00 += first ? v0 : 0.0f;
      a01 += first ? 0.0f : v0;
      a10 += first ? v1 : 0.0f;
      a11 += first ? 0.0f : v1;
    }
    y00 = mml_f(a00); y01 = mml_f(a01);
    y10 = mml_f(a10); y11 = mml_f(a11);
    *(float2*)&(X0 + (cur ^ 1) * NN)[n0] = make_float2(y00, y01);
    *(float2*)&(X1 + (cur ^ 1) * NN)[n0] = make_float2(y10, y11);
    __syncthreads();                             // one barrier per step
    cur ^= 1;
  }

  // final values still in registers
  *(float2*)&out[(size_t)s0 * NN + n0]       = make_float2(y00, y01);
  *(float2*)&out[(size_t)(s0 + 1) * NN + n0] = make_float2(y10, y11);
}

extern "C" void kernel_launch(void* const* d_in, const int* in_sizes, int n_in,
                              void* d_out, int out_size, void* d_ws, size_t ws_size,
                              hipStream_t stream) {
  const float* Xfull = (const float*)d_in[0];   // (B, N) f32
  const float* W     = (const float*)d_in[1];   // (N, N) f32
  const float* bias  = (const float*)d_in[2];   // (N, 1) f32
  float* out = (float*)d_out;

  // ws: pg[EMAX] uint2 (80KB) | cnt[NN] i32 | base[NN+1] i32
  char* ws = (char*)d_ws;
  uint2* pg = (uint2*)ws;
  int* cnt  = (int*)(ws + (size_t)EMAX * 8);
  int* base = (int*)(ws + (size_t)EMAX * 8 + (size_t)NN * 4);

  const int B = in_sizes[0] / NN;   // 512

  hipFuncSetAttribute((const void*)sim,
                      hipFuncAttributeMaxDynamicSharedMemorySize, LDS_TOTAL);

  // zero edge tail (never dereferenced via CSR, but keep LDS contents defined)
  hipMemsetAsync(pg, 0, (size_t)EMAX * 8, stream);
  count_row<<<NN, 64, 0, stream>>>(W, cnt);
  scan2048<<<1, 1024, 0, stream>>>(cnt, base);
  fill_edges<<<NN, 64, 0, stream>>>(W, base, pg);
  sim<<<B / SPB, TPB, LDS_TOTAL, stream>>>(Xfull, bias, pg, base, out);
}

// Round 9
// 159.540 us; speedup vs baseline: 4.6693x; 1.1637x over previous
//
#include <hip/hip_runtime.h>

// SignalingModel: X_{t+1} = mml(W @ X_t + X_bias), 60 steps, W 0.24% sparse.
// R6 = R5 + two per-edge cost cuts:
//  (1) sample-interleaved state float2 X[node] -> ONE ds_read_b64 gathers both
//      samples; init/store become b128.
//  (2) per-node split loops [b0,bm),[bm,b2) -> mid-split select (cmp+4 cndmask
//      +4 add) eliminated; per edge = {b64 entry, b64 gather, 2 fma}.
// Lessons: LDS atomics ~16-25cy (R1/R3); per-step global structure re-reads
// = 20x transaction expansion (R4); VALU-issue-bound at R5 (84% VALUBusy).

#define NN 2048
#define STEPS 60
#define LEAKV 0.01f
#define EMAX 10240
#define TPB 1024
#define SPB 2
#define LDS_ENTRIES (EMAX * 8)                       // 81920 B
#define LDS_TOTAL (LDS_ENTRIES + SPB * 2 * NN * 4)   // 114688 B (112 KB)

__device__ __forceinline__ float mml_f(float x) {
  if (x < 0.0f)      return LEAKV * x;
  else if (x < 0.5f) return x;
  else               return 1.0f - 0.25f / x;
}

// --- build pipeline: CSR by target (edges sorted by (tgt,src)) ------------

__global__ __launch_bounds__(64) void count_row(const float* __restrict__ W,
                                                int* __restrict__ cnt) {
  const int n = blockIdx.x, lane = threadIdx.x;
  int c = 0;
  for (int c0 = 0; c0 < NN; c0 += 64) {
    float w = W[n * NN + c0 + lane];
    c += __popcll(__ballot(w != 0.0f));
  }
  if (lane == 0) cnt[n] = c;
}

__global__ __launch_bounds__(1024) void scan2048(const int* __restrict__ cnt,
                                                 int* __restrict__ base) {
  __shared__ int sb[2][NN];
  const int t = threadIdx.x;
  sb[0][t] = cnt[t];
  sb[0][t + 1024] = cnt[t + 1024];
  __syncthreads();
  int p = 0;
  for (int off = 1; off < NN; off <<= 1) {
    int i0 = t, i1 = t + 1024;
    sb[p ^ 1][i0] = sb[p][i0] + (i0 >= off ? sb[p][i0 - off] : 0);
    sb[p ^ 1][i1] = sb[p][i1] + (i1 >= off ? sb[p][i1 - off] : 0);
    __syncthreads();
    p ^= 1;
  }
  base[t] = sb[p][t] - cnt[t];
  base[t + 1024] = sb[p][t + 1024] - cnt[t + 1024];
  if (t == 1023) base[NN] = sb[p][NN - 1];   // total nnz
}

__global__ __launch_bounds__(64) void fill_edges(const float* __restrict__ W,
                                                 const int* __restrict__ base,
                                                 uint2* __restrict__ pg) {
  const int n = blockIdx.x, lane = threadIdx.x;
  const int b = base[n];
  int off = 0;
  for (int c0 = 0; c0 < NN; c0 += 64) {
    float w = W[n * NN + c0 + lane];
    unsigned long long m = __ballot(w != 0.0f);
    if (w != 0.0f) {
      int e = b + off + __popcll(m & ((1ull << lane) - 1ull));
      pg[e] = make_uint2(__float_as_uint(w), (unsigned)(c0 + lane));
    }
    off += __popcll(m);
  }
}

// --- simulation -----------------------------------------------------------
// one block = 2 samples; thread t owns nodes {2t, 2t+1}; state interleaved
// float2 {sample0, sample1} per node, ping-pong; CSR entries in LDS.
__global__ __launch_bounds__(TPB) void sim(const float* __restrict__ Xfull,
                                           const float* __restrict__ bias,
                                           const uint2* __restrict__ pg,
                                           const int* __restrict__ base,
                                           float* __restrict__ out) {
  extern __shared__ char smem[];
  uint2* E   = (uint2*)smem;                      // [EMAX] CSR entries
  float2* X0 = (float2*)(smem + LDS_ENTRIES);     // [NN] buffer 0 (s0,s1)
  float2* X1 = X0 + NN;                           // [NN] buffer 1

  const int t  = (int)threadIdx.x;
  const int s0 = (int)blockIdx.x * SPB;
  const int n0 = 2 * t;

  // one-time stage: coalesced global b64 -> linear LDS
#pragma unroll
  for (int i = 0; i < EMAX / TPB; ++i) {
    const int e = i * TPB + t;
    E[e] = pg[e];
  }

  const int b0 = base[n0];
  const int bm = base[n0 + 1];
  const int b2 = base[n0 + 2];

  float2 xbA, xbB;   // xb for node n0 / n0+1, component = sample
  {
    const float2 bv = *(const float2*)&bias[n0];
    float2 a = *(const float2*)&Xfull[(size_t)s0 * NN + n0];
    float2 c = *(const float2*)&Xfull[(size_t)(s0 + 1) * NN + n0];
    xbA = make_float2(a.x + bv.x, c.x + bv.x);
    xbB = make_float2(a.y + bv.y, c.y + bv.y);
  }
  // X1 = mml(W@0 + xb) = mml(xb); one b128 store covers both nodes
  *(float4*)&X0[n0] = make_float4(mml_f(xbA.x), mml_f(xbA.y),
                                  mml_f(xbB.x), mml_f(xbB.y));
  __syncthreads();

  float2* cur = X0;
  float2* nxt = X1;
  float2 yA = make_float2(0.f, 0.f), yB = yA;
  for (int it = 0; it < STEPS - 1; ++it) {   // produces X2..X60
    float2 aA = xbA;
    for (int e = b0; e < bm; ++e) {          // node n0 in-edges
      const uint2 en = E[e];
      const float w = __uint_as_float(en.x);
      const float2 v = cur[en.y];            // both samples, one b64
      aA.x += w * v.x;
      aA.y += w * v.y;
    }
    float2 aB = xbB;
    for (int e = bm; e < b2; ++e) {          // node n0+1 in-edges
      const uint2 en = E[e];
      const float w = __uint_as_float(en.x);
      const float2 v = cur[en.y];
      aB.x += w * v.x;
      aB.y += w * v.y;
    }
    yA = make_float2(mml_f(aA.x), mml_f(aA.y));
    yB = make_float2(mml_f(aB.x), mml_f(aB.y));
    *(float4*)&nxt[n0] = make_float4(yA.x, yA.y, yB.x, yB.y);
    __syncthreads();                         // one barrier per step
    float2* tmp = cur; cur = nxt; nxt = tmp;
  }

  // final values still in registers; de-interleave to (B, N) rows
  *(float2*)&out[(size_t)s0 * NN + n0]       = make_float2(yA.x, yB.x);
  *(float2*)&out[(size_t)(s0 + 1) * NN + n0] = make_float2(yA.y, yB.y);
}

extern "C" void kernel_launch(void* const* d_in, const int* in_sizes, int n_in,
                              void* d_out, int out_size, void* d_ws, size_t ws_size,
                              hipStream_t stream) {
  const float* Xfull = (const float*)d_in[0];   // (B, N) f32
  const float* W     = (const float*)d_in[1];   // (N, N) f32
  const float* bias  = (const float*)d_in[2];   // (N, 1) f32
  float* out = (float*)d_out;

  // ws: pg[EMAX] uint2 (80KB) | cnt[NN] i32 | base[NN+1] i32
  char* ws = (char*)d_ws;
  uint2* pg = (uint2*)ws;
  int* cnt  = (int*)(ws + (size_t)EMAX * 8);
  int* base = (int*)(ws + (size_t)EMAX * 8 + (size_t)NN * 4);

  const int B = in_sizes[0] / NN;   // 512

  hipFuncSetAttribute((const void*)sim,
                      hipFuncAttributeMaxDynamicSharedMemorySize, LDS_TOTAL);

  // zero edge tail (CSR never reads past nnz; keep LDS contents defined)
  hipMemsetAsync(pg, 0, (size_t)EMAX * 8, stream);
  count_row<<<NN, 64, 0, stream>>>(W, cnt);
  scan2048<<<1, 1024, 0, stream>>>(cnt, base);
  fill_edges<<<NN, 64, 0, stream>>>(W, base, pg);
  sim<<<B / SPB, TPB, LDS_TOTAL, stream>>>(Xfull, bias, pg, base, out);
}